// Round 2
// baseline (284.521 us; speedup 1.0000x reference)
//
#include <hip/hip_runtime.h>
#include <hip/hip_bf16.h>

// LocalCausalAttention: b=4, t=4096, h=16, d=64, window W=64.
// I/O is float32 (per reference); compute uses bf16 MFMA internally
// (harness tolerance is bf16-grade: 2% rel / bf16-eps floor).
// One workgroup (256 thr = 4 waves) per (batch, t-block, head) tile:
//   Q[64x64] @ K[128x64]^T -> band-masked softmax -> P[64x128] @ V[128x64].

#define TT 4096
#define HH 16
#define DD 64
#define WW 64
#define NBLK (TT / WW)

typedef __attribute__((ext_vector_type(8))) short bf16x8;
typedef __attribute__((ext_vector_type(4))) float f32x4;

static __device__ __forceinline__ ushort f2bf(float x) {
    return __builtin_bit_cast(unsigned short, __float2bfloat16(x));
}

__global__ __launch_bounds__(256, 2)
void lca_fwd(const float* __restrict__ q, const float* __restrict__ k,
             const float* __restrict__ v, const int* __restrict__ am,
             float* __restrict__ out)
{
    const int jb = blockIdx.x;   // t-block 0..63
    const int hi = blockIdx.y;   // head
    const int bi = blockIdx.z;   // batch

    // bf16 tiles; +8-elem (16B) row pad so frag reads spread across bank slots.
    __shared__ ushort sQ[64][72];
    __shared__ ushort sK[128][72];
    __shared__ ushort sVt[64][136];   // V transposed: [d][key]
    __shared__ ushort sP[64][136];    // softmax probs (bf16) [query][key]
    __shared__ int    sKv[128];       // key validity
    __shared__ int    sQv[64];        // query validity

    const int tid = threadIdx.x;
    const size_t rowstride = (size_t)HH * DD;   // f32 elems between tokens
    const size_t qbase = ((size_t)(bi * TT + jb * WW) * HH + hi) * DD;
    const long  kstart = (long)jb * WW - WW;    // token of window row 0

    // ---- stage Q: 64x64 f32 -> bf16. 1024 float4s, 4 passes ----
    #pragma unroll
    for (int p = 0; p < 4; ++p) {
        int idx = p * 256 + tid;
        int row = idx >> 4, c4 = (idx & 15) * 4;
        float4 f = *(const float4*)(q + qbase + (size_t)row * rowstride + c4);
        uint2 u;
        u.x = (uint)f2bf(f.x) | ((uint)f2bf(f.y) << 16);
        u.y = (uint)f2bf(f.z) | ((uint)f2bf(f.w) << 16);
        *(uint2*)(&sQ[row][c4]) = u;
    }
    // ---- stage K: 128x64, zero rows for token < 0 ----
    #pragma unroll
    for (int p = 0; p < 8; ++p) {
        int idx = p * 256 + tid;
        int row = idx >> 4, c4 = (idx & 15) * 4;
        long tok = kstart + row;
        float4 f = make_float4(0.f, 0.f, 0.f, 0.f);
        if (tok >= 0)
            f = *(const float4*)(k + ((size_t)(bi * TT + tok) * HH + hi) * DD + c4);
        uint2 u;
        u.x = (uint)f2bf(f.x) | ((uint)f2bf(f.y) << 16);
        u.y = (uint)f2bf(f.z) | ((uint)f2bf(f.w) << 16);
        *(uint2*)(&sK[row][c4]) = u;
    }
    // ---- stage V transposed: load [key m][d c4..c4+3], scatter sVt[d][m] ----
    #pragma unroll
    for (int p = 0; p < 8; ++p) {
        int idx = p * 256 + tid;
        int row = idx >> 4, c4 = (idx & 15) * 4;   // row = key m, c4 = d
        long tok = kstart + row;
        float4 f = make_float4(0.f, 0.f, 0.f, 0.f);
        if (tok >= 0)
            f = *(const float4*)(v + ((size_t)(bi * TT + tok) * HH + hi) * DD + c4);
        sVt[c4 + 0][row] = f2bf(f.x);
        sVt[c4 + 1][row] = f2bf(f.y);
        sVt[c4 + 2][row] = f2bf(f.z);
        sVt[c4 + 3][row] = f2bf(f.w);
    }
    // ---- validity ----
    if (tid < 128) {
        long tok = kstart + tid;
        sKv[tid] = (tok >= 0) && (am[(size_t)bi * TT + tok] != 0);
    } else if (tid < 192) {
        int r = tid - 128;
        sQv[r] = (am[(size_t)bi * TT + jb * WW + r] != 0);
    }
    __syncthreads();

    const int wv = tid >> 6, lane = tid & 63;
    const int quad = lane >> 4, l15 = lane & 15;
    const int r0 = 16 * wv + quad * 4;        // C-layout base row for this lane

    // ---- S = Q K^T : wave wv owns S rows [16wv, 16wv+16), all 128 cols ----
    bf16x8 aq0 = *(const bf16x8*)(&sQ[16 * wv + l15][quad * 8]);
    bf16x8 aq1 = *(const bf16x8*)(&sQ[16 * wv + l15][32 + quad * 8]);

    f32x4 acc[8];
    #pragma unroll
    for (int kt = 0; kt < 8; ++kt) {
        f32x4 a = {0.f, 0.f, 0.f, 0.f};
        bf16x8 b0 = *(const bf16x8*)(&sK[16 * kt + l15][quad * 8]);
        bf16x8 b1 = *(const bf16x8*)(&sK[16 * kt + l15][32 + quad * 8]);
        a = __builtin_amdgcn_mfma_f32_16x16x32_bf16(aq0, b0, a, 0, 0, 0);
        a = __builtin_amdgcn_mfma_f32_16x16x32_bf16(aq1, b1, a, 0, 0, 0);
        acc[kt] = a;
    }

    // ---- masked softmax (scale 1/8 folded into exp2 constant) ----
    const float NEG = -1.0e9f;
    float rmax[4] = {NEG, NEG, NEG, NEG};
    #pragma unroll
    for (int kt = 0; kt < 8; ++kt) {
        int c = 16 * kt + l15;
        int kvc = sKv[c];
        #pragma unroll
        for (int reg = 0; reg < 4; ++reg) {
            int r = r0 + reg;
            bool valid = (c > r) && (c <= r + WW) && kvc;
            float s = valid ? acc[kt][reg] : NEG;
            acc[kt][reg] = s;
            rmax[reg] = fmaxf(rmax[reg], s);
        }
    }
    #pragma unroll
    for (int reg = 0; reg < 4; ++reg) {
        #pragma unroll
        for (int m = 1; m <= 8; m <<= 1)
            rmax[reg] = fmaxf(rmax[reg], __shfl_xor(rmax[reg], m, 64));
    }

    const float CEXP = 0.125f * 1.44269504088896f;  // scale * log2(e)
    float rsum[4] = {0.f, 0.f, 0.f, 0.f};
    #pragma unroll
    for (int kt = 0; kt < 8; ++kt) {
        int c = 16 * kt + l15;
        #pragma unroll
        for (int reg = 0; reg < 4; ++reg) {
            float s = acc[kt][reg];
            // masked entries hold exactly NEG=-1e9; real scores are O(10)
            float pex = (s > -1.0e8f) ? exp2f((s - rmax[reg]) * CEXP) : 0.f;
            rsum[reg] += pex;
            sP[r0 + reg][c] = f2bf(pex);
        }
    }
    float rden[4];
    #pragma unroll
    for (int reg = 0; reg < 4; ++reg) {
        #pragma unroll
        for (int m = 1; m <= 8; m <<= 1)
            rsum[reg] += __shfl_xor(rsum[reg], m, 64);
        rden[reg] = (rsum[reg] > 0.f ? 1.f / rsum[reg] : 0.f)
                    * (float)sQv[r0 + reg];
    }

    __syncthreads();

    // ---- O = P V : wave wv owns O rows [16wv, 16wv+16), all 64 cols ----
    bf16x8 ap[4];
    #pragma unroll
    for (int kc = 0; kc < 4; ++kc)
        ap[kc] = *(const bf16x8*)(&sP[16 * wv + l15][kc * 32 + quad * 8]);

    #pragma unroll
    for (int nt = 0; nt < 4; ++nt) {
        f32x4 a = {0.f, 0.f, 0.f, 0.f};
        #pragma unroll
        for (int kc = 0; kc < 4; ++kc) {
            bf16x8 bv = *(const bf16x8*)(&sVt[16 * nt + l15][kc * 32 + quad * 8]);
            a = __builtin_amdgcn_mfma_f32_16x16x32_bf16(ap[kc], bv, a, 0, 0, 0);
        }
        #pragma unroll
        for (int reg = 0; reg < 4; ++reg)
            out[qbase + (size_t)(r0 + reg) * rowstride + 16 * nt + l15]
                = a[reg] * rden[reg];
    }
}

extern "C" void kernel_launch(void* const* d_in, const int* in_sizes, int n_in,
                              void* d_out, int out_size, void* d_ws, size_t ws_size,
                              hipStream_t stream) {
    const float* q  = (const float*)d_in[0];
    const float* k  = (const float*)d_in[1];
    const float* v  = (const float*)d_in[2];
    const int*   am = (const int*)d_in[3];
    float* out = (float*)d_out;

    const int b = in_sizes[3] / TT;   // 4
    dim3 grid(NBLK, HH, b);
    dim3 block(256);
    lca_fwd<<<grid, block, 0, stream>>>(q, k, v, am, out);
}

// Round 3
// 228.473 us; speedup vs baseline: 1.2453x; 1.2453x over previous
//
#include <hip/hip_runtime.h>
#include <hip/hip_bf16.h>

// LocalCausalAttention: b=4, t=4096, h=16, d=64, window W=64.
// I/O f32, internal compute bf16 MFMA. One WG (4 waves) per (b, t-block, head):
//   Q[64x64] @ K[128x64]^T -> band-masked softmax -> P[64x128] @ V[128x64].
// R3: LDS union (sP over sQ/sK) -> 44.8KB -> 3 blocks/CU; batched staging loads.

#define TT 4096
#define HH 16
#define DD 64
#define WW 64
#define NBLK (TT / WW)

typedef __attribute__((ext_vector_type(8))) short bf16x8;
typedef __attribute__((ext_vector_type(4))) float f32x4;

static __device__ __forceinline__ ushort f2bf(float x) {
    return __builtin_bit_cast(unsigned short, __float2bfloat16(x));
}
static __device__ __forceinline__ uint pack2(float a, float b) {
    return (uint)f2bf(a) | ((uint)f2bf(b) << 16);
}

__global__ __launch_bounds__(256, 3)
void lca_fwd(const float* __restrict__ q, const float* __restrict__ k,
             const float* __restrict__ v, const int* __restrict__ am,
             float* __restrict__ out)
{
    const int jb = blockIdx.x;   // t-block
    const int hi = blockIdx.y;   // head
    const int bi = blockIdx.z;   // batch

    // sQ/sK dead after QK^T; sP overlays them (27.6KB >= 17.4KB).
    __shared__ union {
        struct { ushort Q[64][72]; ushort K[128][72]; } qk;
        ushort P[64][136];
    } u;
    __shared__ ushort sVt[64][136];   // V transposed [d][key]
    __shared__ int    sKv[128];
    __shared__ int    sQv[64];

    const int tid = threadIdx.x;
    const size_t rowstride = (size_t)HH * DD;
    const size_t qbase = ((size_t)(bi * TT + jb * WW) * HH + hi) * DD;
    const long  kstart = (long)jb * WW - WW;

    // ---- validity first (overlaps with batched loads below) ----
    if (tid < 128) {
        long tok = kstart + tid;
        sKv[tid] = (tok >= 0) && (am[(size_t)bi * TT + tok] != 0);
    } else if (tid < 192) {
        int r = tid - 128;
        sQv[r] = (am[(size_t)bi * TT + jb * WW + r] != 0);
    }

    // ---- batched global loads: all 20 float4 in flight before converts ----
    float4 fq[4], fk[8], fv[8];
    #pragma unroll
    for (int p = 0; p < 4; ++p) {
        int idx = p * 256 + tid;
        int row = idx >> 4, c4 = (idx & 15) * 4;
        fq[p] = *(const float4*)(q + qbase + (size_t)row * rowstride + c4);
    }
    if (jb > 0) {
        #pragma unroll
        for (int p = 0; p < 8; ++p) {
            int idx = p * 256 + tid;
            int row = idx >> 4, c4 = (idx & 15) * 4;
            fk[p] = *(const float4*)(k + ((size_t)(bi * TT + kstart + row) * HH + hi) * DD + c4);
        }
        #pragma unroll
        for (int p = 0; p < 8; ++p) {
            int idx = p * 256 + tid;
            int row = idx >> 4, c4 = (idx & 15) * 4;
            fv[p] = *(const float4*)(v + ((size_t)(bi * TT + kstart + row) * HH + hi) * DD + c4);
        }
    } else {
        // jb==0: rows 0..63 are the zero-pad block; p>=4 <=> row>=64 (uniform per iter)
        #pragma unroll
        for (int p = 0; p < 8; ++p) {
            float4 z = make_float4(0.f, 0.f, 0.f, 0.f);
            if (p >= 4) {
                int idx = p * 256 + tid;
                int row = idx >> 4, c4 = (idx & 15) * 4;
                z = *(const float4*)(k + ((size_t)(bi * TT + (row - 64)) * HH + hi) * DD + c4);
            }
            fk[p] = z;
        }
        #pragma unroll
        for (int p = 0; p < 8; ++p) {
            float4 z = make_float4(0.f, 0.f, 0.f, 0.f);
            if (p >= 4) {
                int idx = p * 256 + tid;
                int row = idx >> 4, c4 = (idx & 15) * 4;
                z = *(const float4*)(v + ((size_t)(bi * TT + (row - 64)) * HH + hi) * DD + c4);
            }
            fv[p] = z;
        }
    }

    // ---- convert + LDS writes ----
    #pragma unroll
    for (int p = 0; p < 4; ++p) {
        int idx = p * 256 + tid;
        int row = idx >> 4, c4 = (idx & 15) * 4;
        uint2 w; w.x = pack2(fq[p].x, fq[p].y); w.y = pack2(fq[p].z, fq[p].w);
        *(uint2*)(&u.qk.Q[row][c4]) = w;
    }
    #pragma unroll
    for (int p = 0; p < 8; ++p) {
        int idx = p * 256 + tid;
        int row = idx >> 4, c4 = (idx & 15) * 4;
        uint2 w; w.x = pack2(fk[p].x, fk[p].y); w.y = pack2(fk[p].z, fk[p].w);
        *(uint2*)(&u.qk.K[row][c4]) = w;
    }
    #pragma unroll
    for (int p = 0; p < 8; ++p) {
        int idx = p * 256 + tid;
        int row = idx >> 4, c4 = (idx & 15) * 4;   // row = key m, c4 = d
        sVt[c4 + 0][row] = f2bf(fv[p].x);
        sVt[c4 + 1][row] = f2bf(fv[p].y);
        sVt[c4 + 2][row] = f2bf(fv[p].z);
        sVt[c4 + 3][row] = f2bf(fv[p].w);
    }
    __syncthreads();   // staging complete

    const int wv = tid >> 6, lane = tid & 63;
    const int quad = lane >> 4, l15 = lane & 15;
    const int r0 = 16 * wv + quad * 4;

    // ---- S = Q K^T : wave wv owns S rows [16wv,16wv+16) x 128 cols ----
    bf16x8 aq0 = *(const bf16x8*)(&u.qk.Q[16 * wv + l15][quad * 8]);
    bf16x8 aq1 = *(const bf16x8*)(&u.qk.Q[16 * wv + l15][32 + quad * 8]);

    f32x4 acc[8];
    #pragma unroll
    for (int kt = 0; kt < 8; ++kt) {
        f32x4 a = {0.f, 0.f, 0.f, 0.f};
        bf16x8 b0 = *(const bf16x8*)(&u.qk.K[16 * kt + l15][quad * 8]);
        bf16x8 b1 = *(const bf16x8*)(&u.qk.K[16 * kt + l15][32 + quad * 8]);
        a = __builtin_amdgcn_mfma_f32_16x16x32_bf16(aq0, b0, a, 0, 0, 0);
        a = __builtin_amdgcn_mfma_f32_16x16x32_bf16(aq1, b1, a, 0, 0, 0);
        acc[kt] = a;
    }
    __syncthreads();   // all waves done reading u.qk before u.P writes

    // ---- masked softmax ----
    const float NEG = -1.0e9f;
    float rmax[4] = {NEG, NEG, NEG, NEG};
    #pragma unroll
    for (int kt = 0; kt < 8; ++kt) {
        int c = 16 * kt + l15;
        int kvc = sKv[c];
        #pragma unroll
        for (int reg = 0; reg < 4; ++reg) {
            int r = r0 + reg;
            bool valid = (c > r) && (c <= r + WW) && kvc;
            float s = valid ? acc[kt][reg] : NEG;
            acc[kt][reg] = s;
            rmax[reg] = fmaxf(rmax[reg], s);
        }
    }
    #pragma unroll
    for (int reg = 0; reg < 4; ++reg) {
        #pragma unroll
        for (int m = 1; m <= 8; m <<= 1)
            rmax[reg] = fmaxf(rmax[reg], __shfl_xor(rmax[reg], m, 64));
    }

    const float CEXP = 0.125f * 1.44269504088896f;  // scale * log2(e)
    float rsum[4] = {0.f, 0.f, 0.f, 0.f};
    #pragma unroll
    for (int kt = 0; kt < 8; ++kt) {
        int c = 16 * kt + l15;
        #pragma unroll
        for (int reg = 0; reg < 4; ++reg) {
            float s = acc[kt][reg];
            float pex = (s > -1.0e8f) ? exp2f((s - rmax[reg]) * CEXP) : 0.f;
            rsum[reg] += pex;
            u.P[r0 + reg][c] = f2bf(pex);
        }
    }
    float rden[4];
    #pragma unroll
    for (int reg = 0; reg < 4; ++reg) {
        #pragma unroll
        for (int m = 1; m <= 8; m <<= 1)
            rsum[reg] += __shfl_xor(rsum[reg], m, 64);
        rden[reg] = (rsum[reg] > 0.f ? 1.f / rsum[reg] : 0.f)
                    * (float)sQv[r0 + reg];
    }

    // No barrier: wave wv reads only u.P rows [16wv,16wv+16) it wrote itself,
    // and sVt was synced at the staging barrier.
    bf16x8 ap[4];
    #pragma unroll
    for (int kc = 0; kc < 4; ++kc)
        ap[kc] = *(const bf16x8*)(&u.P[16 * wv + l15][kc * 32 + quad * 8]);

    #pragma unroll
    for (int nt = 0; nt < 4; ++nt) {
        f32x4 a = {0.f, 0.f, 0.f, 0.f};
        #pragma unroll
        for (int kc = 0; kc < 4; ++kc) {
            bf16x8 bv = *(const bf16x8*)(&sVt[16 * nt + l15][kc * 32 + quad * 8]);
            a = __builtin_amdgcn_mfma_f32_16x16x32_bf16(ap[kc], bv, a, 0, 0, 0);
        }
        #pragma unroll
        for (int reg = 0; reg < 4; ++reg)
            out[qbase + (size_t)(r0 + reg) * rowstride + 16 * nt + l15]
                = a[reg] * rden[reg];
    }
}

extern "C" void kernel_launch(void* const* d_in, const int* in_sizes, int n_in,
                              void* d_out, int out_size, void* d_ws, size_t ws_size,
                              hipStream_t stream) {
    const float* q  = (const float*)d_in[0];
    const float* k  = (const float*)d_in[1];
    const float* v  = (const float*)d_in[2];
    const int*   am = (const int*)d_in[3];
    float* out = (float*)d_out;

    const int b = in_sizes[3] / TT;   // 4
    dim3 grid(NBLK, HH, b);
    dim3 block(256);
    lca_fwd<<<grid, block, 0, stream>>>(q, k, v, am, out);
}